// Round 6
// baseline (384.000 us; speedup 1.0000x reference)
//
#include <hip/hip_runtime.h>

#define HID 2048
#define HEADS 16
#define HD 128
#define BATCH 2
#define S 2048
#define ROWS (BATCH*S)

typedef short short8 __attribute__((ext_vector_type(8)));
typedef unsigned short ushort4v __attribute__((ext_vector_type(4)));
typedef unsigned short ushort2v __attribute__((ext_vector_type(2)));
typedef float f32x4 __attribute__((ext_vector_type(4)));
typedef __bf16 bf16x8 __attribute__((ext_vector_type(8)));
typedef __bf16 bf16x4 __attribute__((ext_vector_type(4)));

static __device__ __forceinline__ float b2f(unsigned short u) {
  union { float f; unsigned int i; } v; v.i = ((unsigned int)u) << 16; return v.f;
}
static __device__ __forceinline__ unsigned short f2b(float f) {
  union { float f; unsigned int i; } v; v.f = f;
  unsigned int u = v.i;
  unsigned int r = ((u >> 16) & 1u) + 0x7fffu;
  return (unsigned short)((u + r) >> 16);
}

// async global->LDS, 16B per lane; LDS dest = wave-uniform base + lane*16 (global src is per-lane)
static __device__ __forceinline__ void gload_lds16(const unsigned short* g, unsigned short* l) {
  __builtin_amdgcn_global_load_lds(
      (const __attribute__((address_space(1))) unsigned int*)(const void*)g,
      (__attribute__((address_space(3))) unsigned int*)(void*)l,
      16, 0, 0);
}

// ---------------- debug fill (ws-size canary) ----------------
__global__ void fill_debug(unsigned short* __restrict__ out, long n) {
  long i = (long)blockIdx.x * blockDim.x + threadIdx.x;
  if (i < n) out[i] = 0x447A;  // bf16 1000.0
}

// ---------------- fused prep: conv repacks + x convert + rope tables + small converts ----------
__global__ void prep_all(const float* __restrict__ c1w, const float* __restrict__ c2w,
                         const float* __restrict__ x, const int* __restrict__ positions,
                         const float* __restrict__ c1b, const float* __restrict__ c2b,
                         const float* __restrict__ rmsw,
                         unsigned short* __restrict__ w1t0, unsigned short* __restrict__ w1t1,
                         unsigned short* __restrict__ w2t0, unsigned short* __restrict__ w2t1,
                         unsigned short* __restrict__ xb,
                         float* __restrict__ ctab, float* __restrict__ stab,
                         unsigned short* __restrict__ c1bb, unsigned short* __restrict__ c2bb,
                         unsigned short* __restrict__ rmswb, unsigned short* __restrict__ zpg) {
  int job = blockIdx.y;
  if (job == 0 || job == 1) {
    const float* w = (job == 0) ? c1w : c2w;
    unsigned short* o0 = (job == 0) ? w1t0 : w2t0;
    unsigned short* o1 = (job == 0) ? w1t1 : w2t1;
    long i = (long)blockIdx.x * 256 + threadIdx.x;
    f32x4 v = *(const f32x4*)(w + i*4);
    ushort2v a = { f2b(v[0]), f2b(v[2]) };
    ushort2v b = { f2b(v[1]), f2b(v[3]) };
    *(ushort2v*)(o0 + i*2) = a;
    *(ushort2v*)(o1 + i*2) = b;
  } else if (job == 2) {
    long i = (long)blockIdx.x * 256 + threadIdx.x;
    #pragma unroll
    for (int rep = 0; rep < 2; ++rep) {
      long idx = i + (long)rep * 1048576L;
      f32x4 v = *(const f32x4*)(x + idx*4);
      ushort4v o = { f2b(v[0]), f2b(v[1]), f2b(v[2]), f2b(v[3]) };
      *(ushort4v*)(xb + idx*4) = o;
    }
  } else {
    int bx = blockIdx.x;
    if (bx < 512) {
      int t = bx * 4 + (threadIdx.x >> 6);
      int i = threadIdx.x & 63;
      float pos = (float)positions[t];
      float inv = powf(10000.0f, -(float)i / 64.0f);
      float ang = pos * inv;
      float sv, cv;
      sincosf(ang, &sv, &cv);
      ctab[t*64 + i] = cv;
      stab[t*64 + i] = sv;
    } else if (bx < 544) {
      int i = (bx - 512) * 256 + threadIdx.x;   // 0..8191
      if (i < 1024) c1bb[i] = f2b(c1b[i]);
      if (i < 2048) { c2bb[i] = f2b(c2b[i]); rmswb[i] = f2b(rmsw[i]); }
      zpg[i] = 0;                               // 8192-ushort zero page (kk-advancing reads)
    }
  }
}

// ---------------- 4x 2048x2048 transpose fp32 [K,N] -> bf16 [N,K], one dispatch ----------------
__global__ void transpose4(const float* __restrict__ s0, const float* __restrict__ s1,
                           const float* __restrict__ s2, const float* __restrict__ s3,
                           unsigned short* __restrict__ d0, unsigned short* __restrict__ d1,
                           unsigned short* __restrict__ d2, unsigned short* __restrict__ d3) {
  __shared__ unsigned short tl[64][73];
  const float* in; unsigned short* out; int perm;
  switch (blockIdx.z) {
    case 0:  in = s0; out = d0; perm = 1; break;
    case 1:  in = s1; out = d1; perm = 1; break;
    case 2:  in = s2; out = d2; perm = 0; break;
    default: in = s3; out = d3; perm = 0; break;
  }
  int n0 = blockIdx.x * 64, k0 = blockIdx.y * 64;
  int tid = threadIdx.x;
  int r = tid >> 3, c8 = (tid & 7) * 8;
  #pragma unroll
  for (int j = 0; j < 2; ++j) {
    int rr = r + j*32;
    const float* p = in + (size_t)(k0 + rr)*HID + n0 + c8;
    f32x4 v0 = *(const f32x4*)p;
    f32x4 v1 = *(const f32x4*)(p + 4);
    #pragma unroll
    for (int e = 0; e < 4; ++e) { tl[rr][c8 + e] = f2b(v0[e]); tl[rr][c8 + 4 + e] = f2b(v1[e]); }
  }
  __syncthreads();
  #pragma unroll
  for (int j = 0; j < 2; ++j) {
    int rr = r + j*32;
    int orow = n0 + rr;
    if (perm) {
      int s5 = (orow >> 5) & 3;
      s5 = (s5 == 1) ? 2 : (s5 == 2) ? 1 : s5;
      orow = (orow & ~127) | (s5 << 5) | (orow & 31);
    }
    short8 v;
    #pragma unroll
    for (int e = 0; e < 8; ++e) v[e] = (short)tl[c8 + e][rr];
    *(short8*)(out + (size_t)orow*HID + k0 + c8) = v;
  }
}

// ================= 128x256-tile GEMM, 3-deep pipeline, strength-reduced staging =========
// (unchanged from round 4 — see comments there)

struct SPtrs { const unsigned short* p[6]; };

static __device__ __forceinline__ void build_ptrs(SPtrs& sp,
    const unsigned short* Ap, const unsigned short* Bp, int Ksz, int sh,
    int m0, int n0, const unsigned short* zpg, int tid) {
  int lane = tid & 63;
  int scol = (((lane & 7) * 16) ^ (((lane >> 3) & 7) << 4)) >> 1;   // swizzled src col (ushorts)
  #pragma unroll
  for (int j = 0; j < 2; ++j) {
    int row = ((tid >> 6) * 2 + j) * 8 + (lane >> 3);               // 0..127
    int gr = m0 + row;
    sp.p[j]     = (sh && ((gr & (S - 1)) == 0)) ? (zpg + scol)
                                                : (Ap + (size_t)(gr - sh)*Ksz + scol);
    sp.p[2 + j] = Bp + (size_t)(n0 + row)*Ksz + scol;
    sp.p[4 + j] = Bp + (size_t)(n0 + 128 + row)*Ksz + scol;
  }
}

static __device__ __forceinline__ void stage6(unsigned short* buf, SPtrs& sp, int tid) {
  int c0 = (tid >> 6) * 1024;            // ushort offset of this wave's 2-chunk pair
  gload_lds16(sp.p[0], buf + c0);
  gload_lds16(sp.p[1], buf + c0 + 512);
  gload_lds16(sp.p[2], buf + 8192  + c0);
  gload_lds16(sp.p[3], buf + 8192  + c0 + 512);
  gload_lds16(sp.p[4], buf + 16384 + c0);
  gload_lds16(sp.p[5], buf + 16384 + c0 + 512);
  #pragma unroll
  for (int i = 0; i < 6; ++i) sp.p[i] += 64;
}

static __device__ __forceinline__ void rd_af(const unsigned short* Ah, bf16x8 (&afr)[4][2],
                                             int wm, int lr, int col0, int axor) {
  #pragma unroll
  for (int mi = 0; mi < 4; ++mi) {
    const unsigned short* rp = Ah + (wm*64 + mi*16 + lr) * 64;
    #pragma unroll
    for (int kk = 0; kk < 2; ++kk)
      afr[mi][kk] = *(const bf16x8*)(rp + (((kk*64 + col0) ^ axor) >> 1));
  }
}
static __device__ __forceinline__ void rd_bf(const unsigned short* Bh, bf16x8 (&bfr)[2][2],
                                             int wn, int lr, int col0, int axor) {
  #pragma unroll
  for (int ni = 0; ni < 2; ++ni) {
    const unsigned short* rp = Bh + (wn*32 + ni*16 + lr) * 64;
    #pragma unroll
    for (int kk = 0; kk < 2; ++kk)
      bfr[ni][kk] = *(const bf16x8*)(rp + (((kk*64 + col0) ^ axor) >> 1));
  }
}
static __device__ __forceinline__ void mfma16(const bf16x8 (&afr)[4][2], const bf16x8 (&bfr)[2][2],
                                              f32x4 (&ac)[4][2]) {
  #pragma unroll
  for (int kk = 0; kk < 2; ++kk)
    #pragma unroll
    for (int mi = 0; mi < 4; ++mi)
      #pragma unroll
      for (int ni = 0; ni < 2; ++ni)
        ac[mi][ni] = __builtin_amdgcn_mfma_f32_16x16x32_bf16(afr[mi][kk], bfr[ni][kk], ac[mi][ni], 0, 0, 0);
}

static __device__ __forceinline__ void gemm8_core(
    unsigned short* lds,
    const unsigned short* __restrict__ A1, const unsigned short* __restrict__ A2,
    const unsigned short* __restrict__ B1, const unsigned short* __restrict__ B2,
    int K1, int K2,
    const unsigned short* __restrict__ bias, const unsigned short* __restrict__ resid,
    void* __restrict__ Cout, int outmode, int N, int m0, int n0,
    int a1shift, const unsigned short* __restrict__ zrow) {
  int tid = threadIdx.x;
  int lane = tid & 63, w = tid >> 6;
  int wm = w >> 2, wn = w & 3;
  int lr = lane & 15, g = lane >> 4;
  int col0 = g * 16;                 // byte col block of this lane's fragment
  int axor = (lr & 7) << 4;          // read-side swizzle (row&7 == lr&7 for all frag rows)
  int nk1 = K1 >> 6;                 // tiles in segment 1 (>= 2 for all call sites)
  int nk = (K1 + K2) >> 6;
  f32x4 acc[2][4][2] = {};
  bf16x8 afr[4][2], bfr0[2][2], bfr1[2][2];

  unsigned short* buf0 = lds;            // each buf: A @0, B0 @8192, B1 @16384 (ushorts)
  unsigned short* buf1 = lds + 24576;
  unsigned short* buf2 = lds + 49152;

  SPtrs sp;
  build_ptrs(sp, A1, B1, K1, a1shift, m0, n0, zrow, tid);

  // ---- prologue: stage tiles 0 and 1; loop's t=0 sync verifies tile 0 ----
  stage6(buf0, sp, tid);
  stage6(buf1, sp, tid);

  unsigned short* cur = buf0;
  unsigned short* nx1 = buf1;
  unsigned short* nx2 = buf2;
  for (int t = 0; t < nk; ++t) {
    // ---- single sync point per K-tile ----
    if (t < nk - 1) asm volatile("s_waitcnt vmcnt(6)" ::: "memory");
    else            asm volatile("s_waitcnt vmcnt(0)" ::: "memory");
    __builtin_amdgcn_s_barrier();
    asm volatile("" ::: "memory");     // no LDS reads hoist above the barrier

    // ---- reads first (critical path), then stage t+2, then MFMA ----
    rd_af(cur,         afr,  wm, lr, col0, axor);
    rd_bf(cur + 8192,  bfr0, wn, lr, col0, axor);
    rd_bf(cur + 16384, bfr1, wn, lr, col0, axor);
    if (t + 2 < nk) {
      if (t + 2 == nk1) build_ptrs(sp, A2, B2, K2, 0, m0, n0, zrow, tid);
      stage6(nx2, sp, tid);
    }
    __builtin_amdgcn_s_setprio(1);
    mfma16(afr, bfr0, acc[0]);
    mfma16(afr, bfr1, acc[1]);
    __builtin_amdgcn_s_setprio(0);

    unsigned short* tmp = cur; cur = nx1; nx1 = nx2; nx2 = tmp;
  }

  // ---- epilogue ----
  #pragma unroll
  for (int qn = 0; qn < 2; ++qn)
    #pragma unroll
    for (int mi = 0; mi < 4; ++mi) {
      int row0 = m0 + wm*64 + mi*16 + g*4;
      #pragma unroll
      for (int ni = 0; ni < 2; ++ni) {
        int col = n0 + qn*128 + wn*32 + ni*16 + lr;
        float bv = bias ? b2f(bias[col]) : 0.f;
        f32x4 a = acc[qn][mi][ni];
        if (outmode == 3) {
          int bb = row0 >> 11;
          int s0 = row0 & (S - 1);
          size_t base = ((size_t)bb * HID + col) * S + s0;
          ushort4v pk;
          #pragma unroll
          for (int j = 0; j < 4; ++j) pk[j] = f2b(a[j]);
          *(ushort4v*)((unsigned short*)Cout + base) = pk;
        } else {
          #pragma unroll
          for (int j = 0; j < 4; ++j) {
            size_t idx = (size_t)(row0 + j) * N + col;
            float v = a[j] + bv;
            if (resid) v += b2f(resid[idx]);
            if (outmode == 1) ((float*)Cout)[idx] = v;
            else ((unsigned short*)Cout)[idx] = f2b(v);
          }
        }
      }
    }
}

template<int SHIFT>
__launch_bounds__(512, 1)
__global__ void gemm8_bt(const unsigned short* __restrict__ A1,
                         const unsigned short* __restrict__ A2,
                         const unsigned short* __restrict__ B1,
                         const unsigned short* __restrict__ B2,
                         int K1, int K2,
                         const unsigned short* __restrict__ bias,
                         const unsigned short* __restrict__ resid,
                         void* __restrict__ Cout, int outmode, int N,
                         const unsigned short* __restrict__ zrow) {
  __shared__ __align__(16) unsigned short lds[73728];   // 144 KiB, 3 bufs
  gemm8_core(lds, A1, A2, B1, B2, K1, K2, bias, resid, Cout, outmode, N,
             blockIdx.x*128, blockIdx.y*256, SHIFT, zrow);
}

// two independent GEMM jobs in one dispatch; heavy job MUST be j0 (dispatched first)
struct GemmJob {
  const unsigned short *A1, *A2, *B1, *B2;
  int K1, K2;
  const unsigned short *bias;
  void* Cout; int outmode; int N; int nby; int a1shift;
};

__launch_bounds__(512, 1)
__global__ void gemm8_dual(GemmJob j0, GemmJob j1, const unsigned short* __restrict__ zrow) {
  __shared__ __align__(16) unsigned short lds[73728];
  int by = blockIdx.y;
  GemmJob j;
  if (by < j0.nby) { j = j0; } else { j = j1; by -= j0.nby; }
  gemm8_core(lds, j.A1, j.A2, j.B1, j.B2, j.K1, j.K2, j.bias, nullptr,
             j.Cout, j.outmode, j.N, blockIdx.x*128, by*256, j.a1shift, zrow);
}

// ---------------- RMSNorm over bf16 rows -> bf16 (single-pass, short8) ----------------
__global__ void rmsnorm_rows(const unsigned short* __restrict__ y,
                             const unsigned short* __restrict__ w,
                             unsigned short* __restrict__ out) {
  int r = blockIdx.x;
  int c8 = threadIdx.x * 8;               // 256 threads x 8 = 2048
  const unsigned short* yr = y + (size_t)r * HID;
  short8 v = *(const short8*)(yr + c8);
  float f[8];
  float ss = 0.f;
  #pragma unroll
  for (int e = 0; e < 8; ++e) { f[e] = b2f((unsigned short)v[e]); ss += f[e]*f[e]; }
  #pragma unroll
  for (int o = 32; o; o >>= 1) ss += __shfl_xor(ss, o);
  __shared__ float red[4];
  if ((threadIdx.x & 63) == 0) red[threadIdx.x >> 6] = ss;
  __syncthreads();
  float tot = red[0] + red[1] + red[2] + red[3];
  float scale = rsqrtf(tot / (float)HID + 1e-6f);
  short8 wv = *(const short8*)(w + c8);
  short8 o8;
  #pragma unroll
  for (int e = 0; e < 8; ++e) o8[e] = (short)f2b(f[e] * scale * b2f((unsigned short)wv[e]));
  *(short8*)(out + (size_t)r*HID + c8) = o8;
}

// ---------------- RoPE from fused qk output [r][4096]; head h = cols h*256..+255 ----------------
__global__ void rope_rearrange(const unsigned short* __restrict__ qkf,
                               const float* __restrict__ ctab, const float* __restrict__ stab,
                               unsigned short* __restrict__ qr, unsigned short* __restrict__ kr) {
  int r = blockIdx.x;
  int t = r & (S - 1);
  int h = threadIdx.x >> 4;
  int i4 = (threadIdx.x & 15) * 4;
  int pc = (i4 & 31) + ((i4 >> 5) << 6);    // permuted col of x1 for elems i4..i4+3 (same 32-block)
  const unsigned short* qk = qkf + (size_t)r * (2*HID) + h * 256;
  f32x4 c = *(const f32x4*)(ctab + t*64 + i4);
  f32x4 s = *(const f32x4*)(stab + t*64 + i4);
  ushort4v q1 = *(const ushort4v*)(qk + pc);
  ushort4v q2 = *(const ushort4v*)(qk + pc + 32);
  ushort4v k1 = *(const ushort4v*)(qk + 128 + pc);
  ushort4v k2 = *(const ushort4v*)(qk + 128 + pc + 32);
  size_t o = (size_t)r * HID + (size_t)h * HD;
  const float SC = 0.08838834764831845f * 1.44269504088896340f;  // 1/sqrt(128) * log2(e)
  ushort4v oq1, oq2, ok1, ok2;
  #pragma unroll
  for (int e = 0; e < 4; ++e) {
    float a = b2f(q1[e]), b = b2f(q2[e]);
    float x = b2f(k1[e]), y = b2f(k2[e]);
    oq1[e] = f2b((a*c[e] - b*s[e]) * SC);
    oq2[e] = f2b((b*c[e] + a*s[e]) * SC);
    ok1[e] = f2b(x*c[e] - y*s[e]);
    ok2[e] = f2b(y*c[e] + x*s[e]);
  }
  *(ushort4v*)(qr + o + i4)      = oq1;
  *(ushort4v*)(qr + o + 64 + i4) = oq2;
  *(ushort4v*)(kr + o + i4)      = ok1;
  *(ushort4v*)(kr + o + 64 + i4) = ok2;
}

// ---------------- MFMA causal flash attention ----------------
// 4 waves/block; wave owns 16 q rows; KV tile 64; swapped QK^T for lane-local softmax.
// K/V/P in XOR-swizzled LDS (ushort_idx ^= (row&7)<<3, same involution write+read; every
// read pattern has row == lr mod 8) -> conflict-free reads, 40KB LDS -> 4 blocks/CU.
// High residency = cross-block MFMA/VALU overlap (softmax is the VALU floor).
#define KT 64

__launch_bounds__(256, 4)
__global__ void attn_mfma(const unsigned short* __restrict__ Qr,
                          const unsigned short* __restrict__ Kr,
                          const unsigned short* __restrict__ Vt,
                          unsigned short* __restrict__ Out) {
  __shared__ __align__(16) unsigned short Kl[64*128];   // [key][d], swizzled
  __shared__ __align__(16) unsigned short Vl[128*64];   // [d][key], swizzled
  __shared__ __align__(16) unsigned short Pl[4*1024];   // per-wave [16 q][64 key] bf16, swizzled
  int tid = threadIdx.x, lane = tid & 63, w = tid >> 6;
  int bh = blockIdx.x;
  int b = bh >> 4, h = bh & 15;
  int qt = (int)gridDim.y - 1 - (int)blockIdx.y;   // big tiles dispatch first
  int q0 = qt * 64;
  size_t bS = (size_t)b * S;
  size_t ho = (size_t)h * HD;
  int lr = lane & 15, g = lane >> 4;
  int rsw = (lr & 7) << 3;                         // read-side swizzle (ushort units)
  bf16x8 bq[4];
  {
    int qrow = q0 + w*16 + lr;
    const unsigned short* qp = Qr + (bS + qrow)*HID + ho + g*8;
    #pragma unroll
    for (int kk = 0; kk < 4; ++kk) bq[kk] = *(const bf16x8*)(qp + kk*32);
  }
  int kR = tid >> 4, kC = (tid & 15) * 8;   // K tile row/col
  int vR = tid >> 3, vC = (tid & 7) * 8;    // V tile row/col
  const unsigned short* Kg = Kr + (bS + kR)*HID + ho + kC;
  const unsigned short* Vg = Vt + ((size_t)b*HID + ho + vR)*S + vC;
  int kwo[4], vwo[4];                       // swizzled write offsets (tile-invariant)
  #pragma unroll
  for (int it = 0; it < 4; ++it) {
    int krow = it*16 + kR;
    kwo[it] = krow*128 + (kC ^ ((krow & 7) << 3));
    int vrow = it*32 + vR;
    vwo[it] = vrow*64 + (vC ^ ((vrow & 7) << 3));
  }
  short8 kreg[4], vreg[4];
  #pragma unroll
  for (int it = 0; it < 4; ++it) {          // prologue: tile 0 -> regs
    kreg[it] = *(const short8*)(Kg + (size_t)(it*16)*HID);
    vreg[it] = *(const short8*)(Vg + (size_t)(it*32)*S);
  }
  f32x4 o[8] = {};                 // O: col(d)=lr+16*ni, row(q_local)=4g+reg
  float m = -1e30f, l = 0.f;
  unsigned short* PlW = Pl + w*1024;
  int ntiles = qt + 1;
  for (int kt = 0; kt < ntiles; ++kt) {
    __syncthreads();
    #pragma unroll
    for (int it = 0; it < 4; ++it) {
      *(short8*)(&Kl[kwo[it]]) = kreg[it];
      *(short8*)(&Vl[vwo[it]]) = vreg[it];
    }
    __syncthreads();
    if (kt + 1 < ntiles) {
      int k1 = (kt + 1) * KT;
      #pragma unroll
      for (int it = 0; it < 4; ++it) {
        kreg[it] = *(const short8*)(Kg + (size_t)(k1 + it*16)*HID);
        vreg[it] = *(const short8*)(Vg + (size_t)(it*32)*S + k1);
      }
    }
    f32x4 st[4] = {};
    __builtin_amdgcn_s_setprio(1);
    #pragma unroll
    for (int kk = 0; kk < 4; ++kk) {
      #pragma unroll
      for (int mi = 0; mi < 4; ++mi) {
        bf16x8 a = *(const bf16x8*)(&Kl[(mi*16 + lr)*128 + ((kk*32 + g*8) ^ rsw)]);
        st[mi] = __builtin_amdgcn_mfma_f32_16x16x32_bf16(a, bq[kk], st[mi], 0, 0, 0);
      }
    }
    __builtin_amdgcn_s_setprio(0);
    bool lastt = (kt == ntiles - 1);
    float tm = -1e30f;
    #pragma unroll
    for (int mi = 0; mi < 4; ++mi)
      #pragma unroll
      for (int r = 0; r < 4; ++r) {
        float v = st[mi][r];
        if (lastt && (mi*16 + 4*g + r) > (w*16 + lr)) v = -1e30f;
        st[mi][r] = v;
        tm = fmaxf(tm, v);
      }
    tm = fmaxf(tm, __shfl_xor(tm, 16));
    tm = fmaxf(tm, __shfl_xor(tm, 32));
    if (!__all(tm - m <= 11.5f)) {
      float mn = fmaxf(m, tm);
      float sc = exp2f(m - mn);
      float s0 = __shfl(sc, 4*g+0), s1 = __shfl(sc, 4*g+1);
      float s2 = __shfl(sc, 4*g+2), s3 = __shfl(sc, 4*g+3);
      #pragma unroll
      for (int ni = 0; ni < 8; ++ni) {
        o[ni][0] *= s0; o[ni][1] *= s1; o[ni][2] *= s2; o[ni][3] *= s3;
      }
      l *= sc;
      m = mn;
    }
    float ts = 0.f;
    __bf16 pbf[4][4];
    #pragma unroll
    for (int mi = 0; mi < 4; ++mi)
      #pragma unroll
      for (int r = 0; r < 4; ++r) {
        float p = exp2f(st[mi][r] - m);
        ts += p;
        pbf[mi][r] = (__bf16)p;
      }
    ts += __shfl_xor(ts, 16);
    ts += __shfl_xor(ts, 32);
    l += ts;
    #pragma unroll
    for (int mi = 0; mi < 4; ++mi) {
      bf16x4 pk = { pbf[mi][0], pbf[mi][1], pbf[mi][2], pbf[mi][3] };
      *(bf16x4*)(&PlW[lr*64 + ((mi*16 + 4*g) ^ rsw)]) = pk;
    }
    asm volatile("" ::: "memory");   // compile-time fence: P stores before P reads
    __builtin_amdgcn_s_setprio(1);
    #pragma unroll
    for (int kk = 0; kk < 2; ++kk) {
      int pc = (kk*32 + g*8) ^ rsw;
      bf16x8 a = *(const bf16x8*)(&PlW[lr*64 + pc]);
      #pragma unroll
      for (int ni = 0; ni < 8; ++ni) {
        bf16x8 bv = *(const bf16x8*)(&Vl[(ni*16 + lr)*64 + pc]);
        o[ni] = __builtin_amdgcn_mfma_f32_16x16x32_bf16(a, bv, o[ni], 0, 0, 0);
      }
    }
    __builtin_amdgcn_s_setprio(0);
  }
  float l0 = __shfl(l, 4*g+0), l1 = __shfl(l, 4*g+1);
  float l2 = __shfl(l, 4*g+2), l3 = __shfl(l, 4*g+3);
  float i0 = 1.f/l0, i1 = 1.f/l1, i2 = 1.f/l2, i3 = 1.f/l3;
  int rbase = q0 + w*16 + 4*g;
  #pragma unroll
  for (int ni = 0; ni < 8; ++ni) {
    size_t cbase = ho + ni*16 + lr;
    Out[(bS + rbase + 0)*HID + cbase] = f2b(o[ni][0]*i0);
    Out[(bS + rbase + 1)*HID + cbase] = f2b(o[ni][1]*i1);
    Out[(bS + rbase + 2)*HID + cbase] = f2b(o[ni][2]*i2);
    Out[(bS + rbase + 3)*HID + cbase] = f2b(o[ni][3]*i3);
  }
}

extern "C" void kernel_launch(void* const* d_in, const int* in_sizes, int n_in,
                              void* d_out, int out_size, void* d_ws, size_t ws_size,
                              hipStream_t stream) {
  const float* x_raw   = (const float*)d_in[0];
  const int* positions = (const int*)d_in[1];
  const float* wq_raw  = (const float*)d_in[2];
  const float* wk_raw  = (const float*)d_in[3];
  const float* wv_raw  = (const float*)d_in[4];
  const float* wo_raw  = (const float*)d_in[5];
  const float* c1w_raw = (const float*)d_in[6];
  const float* c1b_raw = (const float*)d_in[7];
  const float* c2w_raw = (const float*)d_in[8];
  const float* c2b_raw = (const float*)d_in[9];
  const float* rms_raw = (const float*)d_in[10];

  const size_t WS_NEEDED = 140000000;
  if (ws_size < WS_NEEDED) {
    long n = (long)out_size;
    fill_debug<<<dim3((unsigned)((n + 255) / 256)), dim3(256), 0, stream>>>((unsigned short*)d_out, n);
    return;
  }

  char* ws = (char*)d_ws;
  size_t off = 0;
  auto alloc = [&](size_t bytes) { char* p = ws + off; off += (bytes + 255) & ~(size_t)255; return p; };
  float* ctab          = (float*)alloc((size_t)S*64*4);
  float* stab          = (float*)alloc((size_t)S*64*4);
  unsigned short* wqkt = (unsigned short*)alloc((size_t)2*HID*HID*2);  // [wq^T ; wk^T], rope-permuted
  unsigned short* wvt  = (unsigned short*)alloc((size_t)HID*HID*2);
  unsigned short* wot  = (unsigned short*)alloc((size_t)HID*HID*2);
  unsigned short* w1t0 = (unsigned short*)alloc((size_t)1024*HID*2);
  unsigned short* w1t1 = (unsigned short*)alloc((size_t)1024*HID*2);
  unsigned short* w2t0 = (unsigned short*)alloc((size_t)HID*1024*2);
  unsigned short* w2t1 = (unsigned short*)alloc((size_t)HID*1024*2);
  unsigned short* xb   = (unsigned short*)alloc((size_t)ROWS*HID*2);   // reused as kr after conv2
  unsigned short* qrb  = (unsigned short*)alloc((size_t)ROWS*HID*2);   // q rotated
  unsigned short* o1   = (unsigned short*)alloc((size_t)ROWS*1024*2);
  unsigned short* yb   = (unsigned short*)alloc((size_t)ROWS*HID*2);   // reused as attn out
  unsigned short* hg   = (unsigned short*)alloc((size_t)ROWS*HID*2);
  unsigned short* qkf  = (unsigned short*)alloc((size_t)ROWS*2*HID*2); // fused q|k output
  unsigned short* vtg  = (unsigned short*)alloc((size_t)BATCH*HID*S*2);
  unsigned short* c1bb = (unsigned short*)alloc(1024*2);
  unsigned short* c2bb = (unsigned short*)alloc(2048*2);
  unsigned short* rmswb= (unsigned short*)alloc(2048*2);
  unsigned short* zpg  = (unsigned short*)alloc(8192*2);               // zero page (kk-advancing)
  unsigned short* krr  = xb;     // xb dead after conv2 (resid read)
  unsigned short* attn = yb;     // yb dead after rmsnorm

  dim3 b256(256);
  dim3 b512(512);
  prep_all<<<dim3(4096, 4), b256, 0, stream>>>(c1w_raw, c2w_raw, x_raw, positions,
                                               c1b_raw, c2b_raw, rms_raw,
                                               w1t0, w1t1, w2t0, w2t1, xb,
                                               ctab, stab, c1bb, c2bb, rmswb, zpg);
  transpose4<<<dim3(32,32,4), b256, 0, stream>>>(wq_raw, wk_raw, wv_raw, wo_raw,
                                                 wqkt, wqkt + (size_t)HID*HID, wvt, wot);
  // merged dispatch: conv1 (o1 = shift(xb)@W1_0^T + xb@W1_1^T + b1, N=1024, K=4096)  [HEAVY -> j0]
  //                + V-projection (vtg = xb@wv^T, Vt layout, N=2048, K=2048)
  {
    GemmJob j0 = { xb, xb, w1t0, w1t1, HID, HID, c1bb, o1, 0, 1024, 4, 1 };
    GemmJob j1 = { xb, xb, wvt,  wvt,  HID, 0,   nullptr, vtg, 3, HID, 8, 0 };
    gemm8_dual<<<dim3(ROWS/128, 12), b512, 0, stream>>>(j0, j1, zpg);
  }
  // conv2 + resid: yb = shift(o1)@W2_0^T + o1@W2_1^T + b2 + xb    [4096 x 2048]
  gemm8_bt<1><<<dim3(ROWS/128, HID/256), b512, 0, stream>>>(o1, o1, w2t0, w2t1, 1024, 1024, c2bb, xb, yb, 0, HID, zpg);
  rmsnorm_rows<<<dim3(ROWS), b256, 0, stream>>>(yb, rmswb, hg);
  // fused q|k projection: qkf = hg @ [wq|wk] (permuted weight cols)   [4096 x 4096]
  gemm8_bt<0><<<dim3(ROWS/128, (2*HID)/256), b512, 0, stream>>>(hg, hg, wqkt, wqkt, HID, 0, nullptr, nullptr, qkf, 0, 2*HID, nullptr);
  rope_rearrange<<<dim3(ROWS), b256, 0, stream>>>(qkf, ctab, stab, qrb, krr);
  attn_mfma<<<dim3(BATCH*HEADS, S/64), b256, 0, stream>>>(qrb, krr, vtg, attn);
  gemm8_bt<0><<<dim3(ROWS/128, HID/256), b512, 0, stream>>>(attn, attn, wot, wot, HID, 0, nullptr, nullptr, d_out, 1, HID, nullptr);
}

// Round 7
// 371.066 us; speedup vs baseline: 1.0349x; 1.0349x over previous
//
#include <hip/hip_runtime.h>

#define HID 2048
#define HEADS 16
#define HD 128
#define BATCH 2
#define S 2048
#define ROWS (BATCH*S)

typedef short short8 __attribute__((ext_vector_type(8)));
typedef unsigned short ushort4v __attribute__((ext_vector_type(4)));
typedef unsigned short ushort2v __attribute__((ext_vector_type(2)));
typedef float f32x4 __attribute__((ext_vector_type(4)));
typedef __bf16 bf16x8 __attribute__((ext_vector_type(8)));
typedef __bf16 bf16x4 __attribute__((ext_vector_type(4)));

static __device__ __forceinline__ float b2f(unsigned short u) {
  union { float f; unsigned int i; } v; v.i = ((unsigned int)u) << 16; return v.f;
}
static __device__ __forceinline__ unsigned short f2b(float f) {
  union { float f; unsigned int i; } v; v.f = f;
  unsigned int u = v.i;
  unsigned int r = ((u >> 16) & 1u) + 0x7fffu;
  return (unsigned short)((u + r) >> 16);
}

// async global->LDS, 16B per lane; LDS dest = wave-uniform base + lane*16 (global src is per-lane)
static __device__ __forceinline__ void gload_lds16(const unsigned short* g, unsigned short* l) {
  __builtin_amdgcn_global_load_lds(
      (const __attribute__((address_space(1))) unsigned int*)(const void*)g,
      (__attribute__((address_space(3))) unsigned int*)(void*)l,
      16, 0, 0);
}

// ---------------- debug fill (ws-size canary) ----------------
__global__ void fill_debug(unsigned short* __restrict__ out, long n) {
  long i = (long)blockIdx.x * blockDim.x + threadIdx.x;
  if (i < n) out[i] = 0x447A;  // bf16 1000.0
}

// ---------------- fused prep: conv repacks + x convert + rope tables + small converts ----------
__global__ void prep_all(const float* __restrict__ c1w, const float* __restrict__ c2w,
                         const float* __restrict__ x, const int* __restrict__ positions,
                         const float* __restrict__ c1b, const float* __restrict__ c2b,
                         const float* __restrict__ rmsw,
                         unsigned short* __restrict__ w1t0, unsigned short* __restrict__ w1t1,
                         unsigned short* __restrict__ w2t0, unsigned short* __restrict__ w2t1,
                         unsigned short* __restrict__ xb,
                         float* __restrict__ ctab, float* __restrict__ stab,
                         unsigned short* __restrict__ c1bb, unsigned short* __restrict__ c2bb,
                         unsigned short* __restrict__ rmswb, unsigned short* __restrict__ zpg) {
  int job = blockIdx.y;
  if (job == 0 || job == 1) {
    const float* w = (job == 0) ? c1w : c2w;
    unsigned short* o0 = (job == 0) ? w1t0 : w2t0;
    unsigned short* o1 = (job == 0) ? w1t1 : w2t1;
    long i = (long)blockIdx.x * 256 + threadIdx.x;
    f32x4 v = *(const f32x4*)(w + i*4);
    ushort2v a = { f2b(v[0]), f2b(v[2]) };
    ushort2v b = { f2b(v[1]), f2b(v[3]) };
    *(ushort2v*)(o0 + i*2) = a;
    *(ushort2v*)(o1 + i*2) = b;
  } else if (job == 2) {
    long i = (long)blockIdx.x * 256 + threadIdx.x;
    #pragma unroll
    for (int rep = 0; rep < 2; ++rep) {
      long idx = i + (long)rep * 1048576L;
      f32x4 v = *(const f32x4*)(x + idx*4);
      ushort4v o = { f2b(v[0]), f2b(v[1]), f2b(v[2]), f2b(v[3]) };
      *(ushort4v*)(xb + idx*4) = o;
    }
  } else {
    int bx = blockIdx.x;
    if (bx < 512) {
      int t = bx * 4 + (threadIdx.x >> 6);
      int i = threadIdx.x & 63;
      float pos = (float)positions[t];
      float inv = powf(10000.0f, -(float)i / 64.0f);
      float ang = pos * inv;
      float sv, cv;
      sincosf(ang, &sv, &cv);
      ctab[t*64 + i] = cv;
      stab[t*64 + i] = sv;
    } else if (bx < 544) {
      int i = (bx - 512) * 256 + threadIdx.x;   // 0..8191
      if (i < 1024) c1bb[i] = f2b(c1b[i]);
      if (i < 2048) { c2bb[i] = f2b(c2b[i]); rmswb[i] = f2b(rmsw[i]); }
      zpg[i] = 0;                               // 8192-ushort zero page (kk-advancing reads)
    }
  }
}

// ---------------- 4x 2048x2048 transpose fp32 [K,N] -> bf16 [N,K], one dispatch ----------------
__global__ void transpose4(const float* __restrict__ s0, const float* __restrict__ s1,
                           const float* __restrict__ s2, const float* __restrict__ s3,
                           unsigned short* __restrict__ d0, unsigned short* __restrict__ d1,
                           unsigned short* __restrict__ d2, unsigned short* __restrict__ d3) {
  __shared__ unsigned short tl[64][73];
  const float* in; unsigned short* out; int perm;
  switch (blockIdx.z) {
    case 0:  in = s0; out = d0; perm = 1; break;
    case 1:  in = s1; out = d1; perm = 1; break;
    case 2:  in = s2; out = d2; perm = 0; break;
    default: in = s3; out = d3; perm = 0; break;
  }
  int n0 = blockIdx.x * 64, k0 = blockIdx.y * 64;
  int tid = threadIdx.x;
  int r = tid >> 3, c8 = (tid & 7) * 8;
  #pragma unroll
  for (int j = 0; j < 2; ++j) {
    int rr = r + j*32;
    const float* p = in + (size_t)(k0 + rr)*HID + n0 + c8;
    f32x4 v0 = *(const f32x4*)p;
    f32x4 v1 = *(const f32x4*)(p + 4);
    #pragma unroll
    for (int e = 0; e < 4; ++e) { tl[rr][c8 + e] = f2b(v0[e]); tl[rr][c8 + 4 + e] = f2b(v1[e]); }
  }
  __syncthreads();
  #pragma unroll
  for (int j = 0; j < 2; ++j) {
    int rr = r + j*32;
    int orow = n0 + rr;
    if (perm) {
      int s5 = (orow >> 5) & 3;
      s5 = (s5 == 1) ? 2 : (s5 == 2) ? 1 : s5;
      orow = (orow & ~127) | (s5 << 5) | (orow & 31);
    }
    short8 v;
    #pragma unroll
    for (int e = 0; e < 8; ++e) v[e] = (short)tl[c8 + e][rr];
    *(short8*)(out + (size_t)orow*HID + k0 + c8) = v;
  }
}

// ================= 128x256-tile GEMM, 3-deep pipeline, strength-reduced staging =========
// (unchanged from round 4 — see comments there)

struct SPtrs { const unsigned short* p[6]; };

static __device__ __forceinline__ void build_ptrs(SPtrs& sp,
    const unsigned short* Ap, const unsigned short* Bp, int Ksz, int sh,
    int m0, int n0, const unsigned short* zpg, int tid) {
  int lane = tid & 63;
  int scol = (((lane & 7) * 16) ^ (((lane >> 3) & 7) << 4)) >> 1;   // swizzled src col (ushorts)
  #pragma unroll
  for (int j = 0; j < 2; ++j) {
    int row = ((tid >> 6) * 2 + j) * 8 + (lane >> 3);               // 0..127
    int gr = m0 + row;
    sp.p[j]     = (sh && ((gr & (S - 1)) == 0)) ? (zpg + scol)
                                                : (Ap + (size_t)(gr - sh)*Ksz + scol);
    sp.p[2 + j] = Bp + (size_t)(n0 + row)*Ksz + scol;
    sp.p[4 + j] = Bp + (size_t)(n0 + 128 + row)*Ksz + scol;
  }
}

static __device__ __forceinline__ void stage6(unsigned short* buf, SPtrs& sp, int tid) {
  int c0 = (tid >> 6) * 1024;            // ushort offset of this wave's 2-chunk pair
  gload_lds16(sp.p[0], buf + c0);
  gload_lds16(sp.p[1], buf + c0 + 512);
  gload_lds16(sp.p[2], buf + 8192  + c0);
  gload_lds16(sp.p[3], buf + 8192  + c0 + 512);
  gload_lds16(sp.p[4], buf + 16384 + c0);
  gload_lds16(sp.p[5], buf + 16384 + c0 + 512);
  #pragma unroll
  for (int i = 0; i < 6; ++i) sp.p[i] += 64;
}

static __device__ __forceinline__ void rd_af(const unsigned short* Ah, bf16x8 (&afr)[4][2],
                                             int wm, int lr, int col0, int axor) {
  #pragma unroll
  for (int mi = 0; mi < 4; ++mi) {
    const unsigned short* rp = Ah + (wm*64 + mi*16 + lr) * 64;
    #pragma unroll
    for (int kk = 0; kk < 2; ++kk)
      afr[mi][kk] = *(const bf16x8*)(rp + (((kk*64 + col0) ^ axor) >> 1));
  }
}
static __device__ __forceinline__ void rd_bf(const unsigned short* Bh, bf16x8 (&bfr)[2][2],
                                             int wn, int lr, int col0, int axor) {
  #pragma unroll
  for (int ni = 0; ni < 2; ++ni) {
    const unsigned short* rp = Bh + (wn*32 + ni*16 + lr) * 64;
    #pragma unroll
    for (int kk = 0; kk < 2; ++kk)
      bfr[ni][kk] = *(const bf16x8*)(rp + (((kk*64 + col0) ^ axor) >> 1));
  }
}
static __device__ __forceinline__ void mfma16(const bf16x8 (&afr)[4][2], const bf16x8 (&bfr)[2][2],
                                              f32x4 (&ac)[4][2]) {
  #pragma unroll
  for (int kk = 0; kk < 2; ++kk)
    #pragma unroll
    for (int mi = 0; mi < 4; ++mi)
      #pragma unroll
      for (int ni = 0; ni < 2; ++ni)
        ac[mi][ni] = __builtin_amdgcn_mfma_f32_16x16x32_bf16(afr[mi][kk], bfr[ni][kk], ac[mi][ni], 0, 0, 0);
}

static __device__ __forceinline__ void gemm8_core(
    unsigned short* lds,
    const unsigned short* __restrict__ A1, const unsigned short* __restrict__ A2,
    const unsigned short* __restrict__ B1, const unsigned short* __restrict__ B2,
    int K1, int K2,
    const unsigned short* __restrict__ bias, const unsigned short* __restrict__ resid,
    void* __restrict__ Cout, int outmode, int N, int m0, int n0,
    int a1shift, const unsigned short* __restrict__ zrow) {
  int tid = threadIdx.x;
  int lane = tid & 63, w = tid >> 6;
  int wm = w >> 2, wn = w & 3;
  int lr = lane & 15, g = lane >> 4;
  int col0 = g * 16;                 // byte col block of this lane's fragment
  int axor = (lr & 7) << 4;          // read-side swizzle (row&7 == lr&7 for all frag rows)
  int nk1 = K1 >> 6;                 // tiles in segment 1 (>= 2 for all call sites)
  int nk = (K1 + K2) >> 6;
  f32x4 acc[2][4][2] = {};
  bf16x8 afr[4][2], bfr0[2][2], bfr1[2][2];

  unsigned short* buf0 = lds;            // each buf: A @0, B0 @8192, B1 @16384 (ushorts)
  unsigned short* buf1 = lds + 24576;
  unsigned short* buf2 = lds + 49152;

  SPtrs sp;
  build_ptrs(sp, A1, B1, K1, a1shift, m0, n0, zrow, tid);

  // ---- prologue: stage tiles 0 and 1; loop's t=0 sync verifies tile 0 ----
  stage6(buf0, sp, tid);
  stage6(buf1, sp, tid);

  unsigned short* cur = buf0;
  unsigned short* nx1 = buf1;
  unsigned short* nx2 = buf2;
  for (int t = 0; t < nk; ++t) {
    // ---- single sync point per K-tile ----
    if (t < nk - 1) asm volatile("s_waitcnt vmcnt(6)" ::: "memory");
    else            asm volatile("s_waitcnt vmcnt(0)" ::: "memory");
    __builtin_amdgcn_s_barrier();
    asm volatile("" ::: "memory");     // no LDS reads hoist above the barrier

    // ---- reads first (critical path), then stage t+2, then MFMA ----
    rd_af(cur,         afr,  wm, lr, col0, axor);
    rd_bf(cur + 8192,  bfr0, wn, lr, col0, axor);
    rd_bf(cur + 16384, bfr1, wn, lr, col0, axor);
    if (t + 2 < nk) {
      if (t + 2 == nk1) build_ptrs(sp, A2, B2, K2, 0, m0, n0, zrow, tid);
      stage6(nx2, sp, tid);
    }
    __builtin_amdgcn_s_setprio(1);
    mfma16(afr, bfr0, acc[0]);
    mfma16(afr, bfr1, acc[1]);
    __builtin_amdgcn_s_setprio(0);

    unsigned short* tmp = cur; cur = nx1; nx1 = nx2; nx2 = tmp;
  }

  // ---- epilogue ----
  #pragma unroll
  for (int qn = 0; qn < 2; ++qn)
    #pragma unroll
    for (int mi = 0; mi < 4; ++mi) {
      int row0 = m0 + wm*64 + mi*16 + g*4;
      #pragma unroll
      for (int ni = 0; ni < 2; ++ni) {
        int col = n0 + qn*128 + wn*32 + ni*16 + lr;
        float bv = bias ? b2f(bias[col]) : 0.f;
        f32x4 a = acc[qn][mi][ni];
        if (outmode == 3) {
          int bb = row0 >> 11;
          int s0 = row0 & (S - 1);
          size_t base = ((size_t)bb * HID + col) * S + s0;
          ushort4v pk;
          #pragma unroll
          for (int j = 0; j < 4; ++j) pk[j] = f2b(a[j]);
          *(ushort4v*)((unsigned short*)Cout + base) = pk;
        } else {
          #pragma unroll
          for (int j = 0; j < 4; ++j) {
            size_t idx = (size_t)(row0 + j) * N + col;
            float v = a[j] + bv;
            if (resid) v += b2f(resid[idx]);
            if (outmode == 1) ((float*)Cout)[idx] = v;
            else ((unsigned short*)Cout)[idx] = f2b(v);
          }
        }
      }
    }
}

template<int SHIFT>
__launch_bounds__(512, 1)
__global__ void gemm8_bt(const unsigned short* __restrict__ A1,
                         const unsigned short* __restrict__ A2,
                         const unsigned short* __restrict__ B1,
                         const unsigned short* __restrict__ B2,
                         int K1, int K2,
                         const unsigned short* __restrict__ bias,
                         const unsigned short* __restrict__ resid,
                         void* __restrict__ Cout, int outmode, int N,
                         const unsigned short* __restrict__ zrow) {
  __shared__ __align__(16) unsigned short lds[73728];   // 144 KiB, 3 bufs
  gemm8_core(lds, A1, A2, B1, B2, K1, K2, bias, resid, Cout, outmode, N,
             blockIdx.x*128, blockIdx.y*256, SHIFT, zrow);
}

// two independent GEMM jobs in one dispatch; heavy job MUST be j0 (dispatched first)
struct GemmJob {
  const unsigned short *A1, *A2, *B1, *B2;
  int K1, K2;
  const unsigned short *bias;
  void* Cout; int outmode; int N; int nby; int a1shift;
};

__launch_bounds__(512, 1)
__global__ void gemm8_dual(GemmJob j0, GemmJob j1, const unsigned short* __restrict__ zrow) {
  __shared__ __align__(16) unsigned short lds[73728];
  int by = blockIdx.y;
  GemmJob j;
  if (by < j0.nby) { j = j0; } else { j = j1; by -= j0.nby; }
  gemm8_core(lds, j.A1, j.A2, j.B1, j.B2, j.K1, j.K2, j.bias, nullptr,
             j.Cout, j.outmode, j.N, blockIdx.x*128, by*256, j.a1shift, zrow);
}

// ---------------- RMSNorm over bf16 rows -> bf16 (single-pass, short8) ----------------
__global__ void rmsnorm_rows(const unsigned short* __restrict__ y,
                             const unsigned short* __restrict__ w,
                             unsigned short* __restrict__ out) {
  int r = blockIdx.x;
  int c8 = threadIdx.x * 8;               // 256 threads x 8 = 2048
  const unsigned short* yr = y + (size_t)r * HID;
  short8 v = *(const short8*)(yr + c8);
  float f[8];
  float ss = 0.f;
  #pragma unroll
  for (int e = 0; e < 8; ++e) { f[e] = b2f((unsigned short)v[e]); ss += f[e]*f[e]; }
  #pragma unroll
  for (int o = 32; o; o >>= 1) ss += __shfl_xor(ss, o);
  __shared__ float red[4];
  if ((threadIdx.x & 63) == 0) red[threadIdx.x >> 6] = ss;
  __syncthreads();
  float tot = red[0] + red[1] + red[2] + red[3];
  float scale = rsqrtf(tot / (float)HID + 1e-6f);
  short8 wv = *(const short8*)(w + c8);
  short8 o8;
  #pragma unroll
  for (int e = 0; e < 8; ++e) o8[e] = (short)f2b(f[e] * scale * b2f((unsigned short)wv[e]));
  *(short8*)(out + (size_t)r*HID + c8) = o8;
}

// ---------------- RoPE from fused qk output [r][4096]; head h = cols h*256..+255 ----------------
__global__ void rope_rearrange(const unsigned short* __restrict__ qkf,
                               const float* __restrict__ ctab, const float* __restrict__ stab,
                               unsigned short* __restrict__ qr, unsigned short* __restrict__ kr) {
  int r = blockIdx.x;
  int t = r & (S - 1);
  int h = threadIdx.x >> 4;
  int i4 = (threadIdx.x & 15) * 4;
  int pc = (i4 & 31) + ((i4 >> 5) << 6);    // permuted col of x1 for elems i4..i4+3 (same 32-block)
  const unsigned short* qk = qkf + (size_t)r * (2*HID) + h * 256;
  f32x4 c = *(const f32x4*)(ctab + t*64 + i4);
  f32x4 s = *(const f32x4*)(stab + t*64 + i4);
  ushort4v q1 = *(const ushort4v*)(qk + pc);
  ushort4v q2 = *(const ushort4v*)(qk + pc + 32);
  ushort4v k1 = *(const ushort4v*)(qk + 128 + pc);
  ushort4v k2 = *(const ushort4v*)(qk + 128 + pc + 32);
  size_t o = (size_t)r * HID + (size_t)h * HD;
  const float SC = 0.08838834764831845f * 1.44269504088896340f;  // 1/sqrt(128) * log2(e)
  ushort4v oq1, oq2, ok1, ok2;
  #pragma unroll
  for (int e = 0; e < 4; ++e) {
    float a = b2f(q1[e]), b = b2f(q2[e]);
    float x = b2f(k1[e]), y = b2f(k2[e]);
    oq1[e] = f2b((a*c[e] - b*s[e]) * SC);
    oq2[e] = f2b((b*c[e] + a*s[e]) * SC);
    ok1[e] = f2b(x*c[e] - y*s[e]);
    ok2[e] = f2b(y*c[e] + x*s[e]);
  }
  *(ushort4v*)(qr + o + i4)      = oq1;
  *(ushort4v*)(qr + o + 64 + i4) = oq2;
  *(ushort4v*)(kr + o + i4)      = ok1;
  *(ushort4v*)(kr + o + 64 + i4) = ok2;
}

// ---------------- MFMA causal flash attention ----------------
// 4 waves/block; wave owns 16 q rows; KV tile 64; swapped QK^T for lane-local softmax.
// K/V/P in XOR-swizzled LDS (ushort_idx ^= (row&7)<<3, same involution write+read) ->
// conflict-free reads. __launch_bounds__(256,3): 170-VGPR budget fits the ~150 live set
// (o[8]+bq+kreg/vreg+st) with NO spill; (256,4) capped at 128 and spilled ~60MB to scratch
// (round-6 counters: VGPR 64, WRITE_SIZE 66MB). 3 blocks/CU suffices for MFMA/VALU overlap.
#define KT 64

__launch_bounds__(256, 3)
__global__ void attn_mfma(const unsigned short* __restrict__ Qr,
                          const unsigned short* __restrict__ Kr,
                          const unsigned short* __restrict__ Vt,
                          unsigned short* __restrict__ Out) {
  __shared__ __align__(16) unsigned short Kl[64*128];   // [key][d], swizzled
  __shared__ __align__(16) unsigned short Vl[128*64];   // [d][key], swizzled
  __shared__ __align__(16) unsigned short Pl[4*1024];   // per-wave [16 q][64 key] bf16, swizzled
  int tid = threadIdx.x, lane = tid & 63, w = tid >> 6;
  int bh = blockIdx.x;
  int b = bh >> 4, h = bh & 15;
  int qt = (int)gridDim.y - 1 - (int)blockIdx.y;   // big tiles dispatch first
  int q0 = qt * 64;
  size_t bS = (size_t)b * S;
  size_t ho = (size_t)h * HD;
  int lr = lane & 15, g = lane >> 4;
  int rsw = (lr & 7) << 3;                         // read-side swizzle (ushort units)
  bf16x8 bq[4];
  {
    int qrow = q0 + w*16 + lr;
    const unsigned short* qp = Qr + (bS + qrow)*HID + ho + g*8;
    #pragma unroll
    for (int kk = 0; kk < 4; ++kk) bq[kk] = *(const bf16x8*)(qp + kk*32);
  }
  int kR = tid >> 4, kC = (tid & 15) * 8;   // K tile row/col
  int vR = tid >> 3, vC = (tid & 7) * 8;    // V tile row/col
  const unsigned short* Kg = Kr + (bS + kR)*HID + ho + kC;
  const unsigned short* Vg = Vt + ((size_t)b*HID + ho + vR)*S + vC;
  int kwo[4], vwo[4];                       // swizzled write offsets (tile-invariant)
  #pragma unroll
  for (int it = 0; it < 4; ++it) {
    int krow = it*16 + kR;
    kwo[it] = krow*128 + (kC ^ ((krow & 7) << 3));
    int vrow = it*32 + vR;
    vwo[it] = vrow*64 + (vC ^ ((vrow & 7) << 3));
  }
  short8 kreg[4], vreg[4];
  #pragma unroll
  for (int it = 0; it < 4; ++it) {          // prologue: tile 0 -> regs
    kreg[it] = *(const short8*)(Kg + (size_t)(it*16)*HID);
    vreg[it] = *(const short8*)(Vg + (size_t)(it*32)*S);
  }
  f32x4 o[8] = {};                 // O: col(d)=lr+16*ni, row(q_local)=4g+reg
  float m = -1e30f, l = 0.f;
  unsigned short* PlW = Pl + w*1024;
  int ntiles = qt + 1;
  for (int kt = 0; kt < ntiles; ++kt) {
    __syncthreads();
    #pragma unroll
    for (int it = 0; it < 4; ++it) {
      *(short8*)(&Kl[kwo[it]]) = kreg[it];
      *(short8*)(&Vl[vwo[it]]) = vreg[it];
    }
    __syncthreads();
    if (kt + 1 < ntiles) {
      int k1 = (kt + 1) * KT;
      #pragma unroll
      for (int it = 0; it < 4; ++it) {
        kreg[it] = *(const short8*)(Kg + (size_t)(k1 + it*16)*HID);
        vreg[it] = *(const short8*)(Vg + (size_t)(it*32)*S + k1);
      }
    }
    f32x4 st[4] = {};
    __builtin_amdgcn_s_setprio(1);
    #pragma unroll
    for (int kk = 0; kk < 4; ++kk) {
      #pragma unroll
      for (int mi = 0; mi < 4; ++mi) {
        bf16x8 a = *(const bf16x8*)(&Kl[(mi*16 + lr)*128 + ((kk*32 + g*8) ^ rsw)]);
        st[mi] = __builtin_amdgcn_mfma_f32_16x16x32_bf16(a, bq[kk], st[mi], 0, 0, 0);
      }
    }
    __builtin_amdgcn_s_setprio(0);
    bool lastt = (kt == ntiles - 1);
    float tm = -1e30f;
    #pragma unroll
    for (int mi = 0; mi < 4; ++mi)
      #pragma unroll
      for (int r = 0; r < 4; ++r) {
        float v = st[mi][r];
        if (lastt && (mi*16 + 4*g + r) > (w*16 + lr)) v = -1e30f;
        st[mi][r] = v;
        tm = fmaxf(tm, v);
      }
    tm = fmaxf(tm, __shfl_xor(tm, 16));
    tm = fmaxf(tm, __shfl_xor(tm, 32));
    if (!__all(tm - m <= 11.5f)) {
      float mn = fmaxf(m, tm);
      float sc = exp2f(m - mn);
      float s0 = __shfl(sc, 4*g+0), s1 = __shfl(sc, 4*g+1);
      float s2 = __shfl(sc, 4*g+2), s3 = __shfl(sc, 4*g+3);
      #pragma unroll
      for (int ni = 0; ni < 8; ++ni) {
        o[ni][0] *= s0; o[ni][1] *= s1; o[ni][2] *= s2; o[ni][3] *= s3;
      }
      l *= sc;
      m = mn;
    }
    float ts = 0.f;
    __bf16 pbf[4][4];
    #pragma unroll
    for (int mi = 0; mi < 4; ++mi)
      #pragma unroll
      for (int r = 0; r < 4; ++r) {
        float p = exp2f(st[mi][r] - m);
        ts += p;
        pbf[mi][r] = (__bf16)p;
      }
    ts += __shfl_xor(ts, 16);
    ts += __shfl_xor(ts, 32);
    l += ts;
    #pragma unroll
    for (int mi = 0; mi < 4; ++mi) {
      bf16x4 pk = { pbf[mi][0], pbf[mi][1], pbf[mi][2], pbf[mi][3] };
      *(bf16x4*)(&PlW[lr*64 + ((mi*16 + 4*g) ^ rsw)]) = pk;
    }
    asm volatile("" ::: "memory");   // compile-time fence: P stores before P reads
    __builtin_amdgcn_s_setprio(1);
    #pragma unroll
    for (int kk = 0; kk < 2; ++kk) {
      int pc = (kk*32 + g*8) ^ rsw;
      bf16x8 a = *(const bf16x8*)(&PlW[lr*64 + pc]);
      #pragma unroll
      for (int ni = 0; ni < 8; ++ni) {
        bf16x8 bv = *(const bf16x8*)(&Vl[(ni*16 + lr)*64 + pc]);
        o[ni] = __builtin_amdgcn_mfma_f32_16x16x32_bf16(a, bv, o[ni], 0, 0, 0);
      }
    }
    __builtin_amdgcn_s_setprio(0);
  }
  float l0 = __shfl(l, 4*g+0), l1 = __shfl(l, 4*g+1);
  float l2 = __shfl(l, 4*g+2), l3 = __shfl(l, 4*g+3);
  float i0 = 1.f/l0, i1 = 1.f/l1, i2 = 1.f/l2, i3 = 1.f/l3;
  int rbase = q0 + w*16 + 4*g;
  #pragma unroll
  for (int ni = 0; ni < 8; ++ni) {
    size_t cbase = ho + ni*16 + lr;
    Out[(bS + rbase + 0)*HID + cbase] = f2b(o[ni][0]*i0);
    Out[(bS + rbase + 1)*HID + cbase] = f2b(o[ni][1]*i1);
    Out[(bS + rbase + 2)*HID + cbase] = f2b(o[ni][2]*i2);
    Out[(bS + rbase + 3)*HID + cbase] = f2b(o[ni][3]*i3);
  }
}

extern "C" void kernel_launch(void* const* d_in, const int* in_sizes, int n_in,
                              void* d_out, int out_size, void* d_ws, size_t ws_size,
                              hipStream_t stream) {
  const float* x_raw   = (const float*)d_in[0];
  const int* positions = (const int*)d_in[1];
  const float* wq_raw  = (const float*)d_in[2];
  const float* wk_raw  = (const float*)d_in[3];
  const float* wv_raw  = (const float*)d_in[4];
  const float* wo_raw  = (const float*)d_in[5];
  const float* c1w_raw = (const float*)d_in[6];
  const float* c1b_raw = (const float*)d_in[7];
  const float* c2w_raw = (const float*)d_in[8];
  const float* c2b_raw = (const float*)d_in[9];
  const float* rms_raw = (const float*)d_in[10];

  const size_t WS_NEEDED = 140000000;
  if (ws_size < WS_NEEDED) {
    long n = (long)out_size;
    fill_debug<<<dim3((unsigned)((n + 255) / 256)), dim3(256), 0, stream>>>((unsigned short*)d_out, n);
    return;
  }

  char* ws = (char*)d_ws;
  size_t off = 0;
  auto alloc = [&](size_t bytes) { char* p = ws + off; off += (bytes + 255) & ~(size_t)255; return p; };
  float* ctab          = (float*)alloc((size_t)S*64*4);
  float* stab          = (float*)alloc((size_t)S*64*4);
  unsigned short* wqkt = (unsigned short*)alloc((size_t)2*HID*HID*2);  // [wq^T ; wk^T], rope-permuted
  unsigned short* wvt  = (unsigned short*)alloc((size_t)HID*HID*2);
  unsigned short* wot  = (unsigned short*)alloc((size_t)HID*HID*2);
  unsigned short* w1t0 = (unsigned short*)alloc((size_t)1024*HID*2);
  unsigned short* w1t1 = (unsigned short*)alloc((size_t)1024*HID*2);
  unsigned short* w2t0 = (unsigned short*)alloc((size_t)HID*1024*2);
  unsigned short* w2t1 = (unsigned short*)alloc((size_t)HID*1024*2);
  unsigned short* xb   = (unsigned short*)alloc((size_t)ROWS*HID*2);   // reused as kr after conv2
  unsigned short* qrb  = (unsigned short*)alloc((size_t)ROWS*HID*2);   // q rotated
  unsigned short* o1   = (unsigned short*)alloc((size_t)ROWS*1024*2);
  unsigned short* yb   = (unsigned short*)alloc((size_t)ROWS*HID*2);   // reused as attn out
  unsigned short* hg   = (unsigned short*)alloc((size_t)ROWS*HID*2);
  unsigned short* qkf  = (unsigned short*)alloc((size_t)ROWS*2*HID*2); // fused q|k output
  unsigned short* vtg  = (unsigned short*)alloc((size_t)BATCH*HID*S*2);
  unsigned short* c1bb = (unsigned short*)alloc(1024*2);
  unsigned short* c2bb = (unsigned short*)alloc(2048*2);
  unsigned short* rmswb= (unsigned short*)alloc(2048*2);
  unsigned short* zpg  = (unsigned short*)alloc(8192*2);               // zero page (kk-advancing)
  unsigned short* krr  = xb;     // xb dead after conv2 (resid read)
  unsigned short* attn = yb;     // yb dead after rmsnorm

  dim3 b256(256);
  dim3 b512(512);
  prep_all<<<dim3(4096, 4), b256, 0, stream>>>(c1w_raw, c2w_raw, x_raw, positions,
                                               c1b_raw, c2b_raw, rms_raw,
                                               w1t0, w1t1, w2t0, w2t1, xb,
                                               ctab, stab, c1bb, c2bb, rmswb, zpg);
  transpose4<<<dim3(32,32,4), b256, 0, stream>>>(wq_raw, wk_raw, wv_raw, wo_raw,
                                                 wqkt, wqkt + (size_t)HID*HID, wvt, wot);
  // merged dispatch: conv1 (o1 = shift(xb)@W1_0^T + xb@W1_1^T + b1, N=1024, K=4096)  [HEAVY -> j0]
  //                + V-projection (vtg = xb@wv^T, Vt layout, N=2048, K=2048)
  {
    GemmJob j0 = { xb, xb, w1t0, w1t1, HID, HID, c1bb, o1, 0, 1024, 4, 1 };
    GemmJob j1 = { xb, xb, wvt,  wvt,  HID, 0,   nullptr, vtg, 3, HID, 8, 0 };
    gemm8_dual<<<dim3(ROWS/128, 12), b512, 0, stream>>>(j0, j1, zpg);
  }
  // conv2 + resid: yb = shift(o1)@W2_0^T + o1@W2_1^T + b2 + xb    [4096 x 2048]
  gemm8_bt<1><<<dim3(ROWS/128, HID/256), b512, 0, stream>>>(o1, o1, w2t0, w2t1, 1024, 1024, c2bb, xb, yb, 0, HID, zpg);
  rmsnorm_rows<<<dim3(ROWS), b256, 0, stream>>>(yb, rmswb, hg);
  // fused q|k projection: qkf = hg @ [wq|wk] (permuted weight cols)   [4096 x 4096]
  gemm8_bt<0><<<dim3(ROWS/128, (2*HID)/256), b512, 0, stream>>>(hg, hg, wqkt, wqkt, HID, 0, nullptr, nullptr, qkf, 0, 2*HID, nullptr);
  rope_rearrange<<<dim3(ROWS), b256, 0, stream>>>(qkf, ctab, stab, qrb, krr);
  attn_mfma<<<dim3(BATCH*HEADS, S/64), b256, 0, stream>>>(qrb, krr, vtg, attn);
  gemm8_bt<0><<<dim3(ROWS/128, HID/256), b512, 0, stream>>>(attn, attn, wot, wot, HID, 0, nullptr, nullptr, d_out, 1, HID, nullptr);
}

// Round 8
// 368.238 us; speedup vs baseline: 1.0428x; 1.0077x over previous
//
#include <hip/hip_runtime.h>

#define HID 2048
#define HEADS 16
#define HD 128
#define BATCH 2
#define S 2048
#define ROWS (BATCH*S)

typedef short short8 __attribute__((ext_vector_type(8)));
typedef unsigned short ushort4v __attribute__((ext_vector_type(4)));
typedef unsigned short ushort2v __attribute__((ext_vector_type(2)));
typedef float f32x4 __attribute__((ext_vector_type(4)));
typedef __bf16 bf16x8 __attribute__((ext_vector_type(8)));
typedef __bf16 bf16x4 __attribute__((ext_vector_type(4)));

static __device__ __forceinline__ float b2f(unsigned short u) {
  union { float f; unsigned int i; } v; v.i = ((unsigned int)u) << 16; return v.f;
}
static __device__ __forceinline__ unsigned short f2b(float f) {
  union { float f; unsigned int i; } v; v.f = f;
  unsigned int u = v.i;
  unsigned int r = ((u >> 16) & 1u) + 0x7fffu;
  return (unsigned short)((u + r) >> 16);
}

// async global->LDS, 16B per lane; LDS dest = wave-uniform base + lane*16 (global src is per-lane)
static __device__ __forceinline__ void gload_lds16(const unsigned short* g, unsigned short* l) {
  __builtin_amdgcn_global_load_lds(
      (const __attribute__((address_space(1))) unsigned int*)(const void*)g,
      (__attribute__((address_space(3))) unsigned int*)(void*)l,
      16, 0, 0);
}

// ---------------- debug fill (ws-size canary) ----------------
__global__ void fill_debug(unsigned short* __restrict__ out, long n) {
  long i = (long)blockIdx.x * blockDim.x + threadIdx.x;
  if (i < n) out[i] = 0x447A;  // bf16 1000.0
}

// ---------------- fused prep: conv repacks + x convert + rope tables + small converts ----------
__global__ void prep_all(const float* __restrict__ c1w, const float* __restrict__ c2w,
                         const float* __restrict__ x, const int* __restrict__ positions,
                         const float* __restrict__ c1b, const float* __restrict__ c2b,
                         const float* __restrict__ rmsw,
                         unsigned short* __restrict__ w1t0, unsigned short* __restrict__ w1t1,
                         unsigned short* __restrict__ w2t0, unsigned short* __restrict__ w2t1,
                         unsigned short* __restrict__ xb,
                         float* __restrict__ ctab, float* __restrict__ stab,
                         unsigned short* __restrict__ c1bb, unsigned short* __restrict__ c2bb,
                         unsigned short* __restrict__ rmswb, unsigned short* __restrict__ zpg) {
  int job = blockIdx.y;
  if (job == 0 || job == 1) {
    const float* w = (job == 0) ? c1w : c2w;
    unsigned short* o0 = (job == 0) ? w1t0 : w2t0;
    unsigned short* o1 = (job == 0) ? w1t1 : w2t1;
    long i = (long)blockIdx.x * 256 + threadIdx.x;
    f32x4 v = *(const f32x4*)(w + i*4);
    ushort2v a = { f2b(v[0]), f2b(v[2]) };
    ushort2v b = { f2b(v[1]), f2b(v[3]) };
    *(ushort2v*)(o0 + i*2) = a;
    *(ushort2v*)(o1 + i*2) = b;
  } else if (job == 2) {
    long i = (long)blockIdx.x * 256 + threadIdx.x;
    #pragma unroll
    for (int rep = 0; rep < 2; ++rep) {
      long idx = i + (long)rep * 1048576L;
      f32x4 v = *(const f32x4*)(x + idx*4);
      ushort4v o = { f2b(v[0]), f2b(v[1]), f2b(v[2]), f2b(v[3]) };
      *(ushort4v*)(xb + idx*4) = o;
    }
  } else {
    int bx = blockIdx.x;
    if (bx < 512) {
      int t = bx * 4 + (threadIdx.x >> 6);
      int i = threadIdx.x & 63;
      float pos = (float)positions[t];
      float inv = powf(10000.0f, -(float)i / 64.0f);
      float ang = pos * inv;
      float sv, cv;
      sincosf(ang, &sv, &cv);
      ctab[t*64 + i] = cv;
      stab[t*64 + i] = sv;
    } else if (bx < 544) {
      int i = (bx - 512) * 256 + threadIdx.x;   // 0..8191
      if (i < 1024) c1bb[i] = f2b(c1b[i]);
      if (i < 2048) { c2bb[i] = f2b(c2b[i]); rmswb[i] = f2b(rmsw[i]); }
      zpg[i] = 0;                               // 8192-ushort zero page (kk-advancing reads)
    }
  }
}

// ---------------- 4x 2048x2048 transpose fp32 [K,N] -> bf16 [N,K], one dispatch ----------------
__global__ void transpose4(const float* __restrict__ s0, const float* __restrict__ s1,
                           const float* __restrict__ s2, const float* __restrict__ s3,
                           unsigned short* __restrict__ d0, unsigned short* __restrict__ d1,
                           unsigned short* __restrict__ d2, unsigned short* __restrict__ d3) {
  __shared__ unsigned short tl[64][73];
  const float* in; unsigned short* out; int perm;
  switch (blockIdx.z) {
    case 0:  in = s0; out = d0; perm = 1; break;
    case 1:  in = s1; out = d1; perm = 1; break;
    case 2:  in = s2; out = d2; perm = 0; break;
    default: in = s3; out = d3; perm = 0; break;
  }
  int n0 = blockIdx.x * 64, k0 = blockIdx.y * 64;
  int tid = threadIdx.x;
  int r = tid >> 3, c8 = (tid & 7) * 8;
  #pragma unroll
  for (int j = 0; j < 2; ++j) {
    int rr = r + j*32;
    const float* p = in + (size_t)(k0 + rr)*HID + n0 + c8;
    f32x4 v0 = *(const f32x4*)p;
    f32x4 v1 = *(const f32x4*)(p + 4);
    #pragma unroll
    for (int e = 0; e < 4; ++e) { tl[rr][c8 + e] = f2b(v0[e]); tl[rr][c8 + 4 + e] = f2b(v1[e]); }
  }
  __syncthreads();
  #pragma unroll
  for (int j = 0; j < 2; ++j) {
    int rr = r + j*32;
    int orow = n0 + rr;
    if (perm) {
      int s5 = (orow >> 5) & 3;
      s5 = (s5 == 1) ? 2 : (s5 == 2) ? 1 : s5;
      orow = (orow & ~127) | (s5 << 5) | (orow & 31);
    }
    short8 v;
    #pragma unroll
    for (int e = 0; e < 8; ++e) v[e] = (short)tl[c8 + e][rr];
    *(short8*)(out + (size_t)orow*HID + k0 + c8) = v;
  }
}

// ================= 128x256-tile GEMM, 3-deep pipeline, strength-reduced staging =========
// (unchanged from round 4 — see comments there)

struct SPtrs { const unsigned short* p[6]; };

static __device__ __forceinline__ void build_ptrs(SPtrs& sp,
    const unsigned short* Ap, const unsigned short* Bp, int Ksz, int sh,
    int m0, int n0, const unsigned short* zpg, int tid) {
  int lane = tid & 63;
  int scol = (((lane & 7) * 16) ^ (((lane >> 3) & 7) << 4)) >> 1;   // swizzled src col (ushorts)
  #pragma unroll
  for (int j = 0; j < 2; ++j) {
    int row = ((tid >> 6) * 2 + j) * 8 + (lane >> 3);               // 0..127
    int gr = m0 + row;
    sp.p[j]     = (sh && ((gr & (S - 1)) == 0)) ? (zpg + scol)
                                                : (Ap + (size_t)(gr - sh)*Ksz + scol);
    sp.p[2 + j] = Bp + (size_t)(n0 + row)*Ksz + scol;
    sp.p[4 + j] = Bp + (size_t)(n0 + 128 + row)*Ksz + scol;
  }
}

static __device__ __forceinline__ void stage6(unsigned short* buf, SPtrs& sp, int tid) {
  int c0 = (tid >> 6) * 1024;            // ushort offset of this wave's 2-chunk pair
  gload_lds16(sp.p[0], buf + c0);
  gload_lds16(sp.p[1], buf + c0 + 512);
  gload_lds16(sp.p[2], buf + 8192  + c0);
  gload_lds16(sp.p[3], buf + 8192  + c0 + 512);
  gload_lds16(sp.p[4], buf + 16384 + c0);
  gload_lds16(sp.p[5], buf + 16384 + c0 + 512);
  #pragma unroll
  for (int i = 0; i < 6; ++i) sp.p[i] += 64;
}

static __device__ __forceinline__ void rd_af(const unsigned short* Ah, bf16x8 (&afr)[4][2],
                                             int wm, int lr, int col0, int axor) {
  #pragma unroll
  for (int mi = 0; mi < 4; ++mi) {
    const unsigned short* rp = Ah + (wm*64 + mi*16 + lr) * 64;
    #pragma unroll
    for (int kk = 0; kk < 2; ++kk)
      afr[mi][kk] = *(const bf16x8*)(rp + (((kk*64 + col0) ^ axor) >> 1));
  }
}
static __device__ __forceinline__ void rd_bf(const unsigned short* Bh, bf16x8 (&bfr)[2][2],
                                             int wn, int lr, int col0, int axor) {
  #pragma unroll
  for (int ni = 0; ni < 2; ++ni) {
    const unsigned short* rp = Bh + (wn*32 + ni*16 + lr) * 64;
    #pragma unroll
    for (int kk = 0; kk < 2; ++kk)
      bfr[ni][kk] = *(const bf16x8*)(rp + (((kk*64 + col0) ^ axor) >> 1));
  }
}
static __device__ __forceinline__ void mfma16(const bf16x8 (&afr)[4][2], const bf16x8 (&bfr)[2][2],
                                              f32x4 (&ac)[4][2]) {
  #pragma unroll
  for (int kk = 0; kk < 2; ++kk)
    #pragma unroll
    for (int mi = 0; mi < 4; ++mi)
      #pragma unroll
      for (int ni = 0; ni < 2; ++ni)
        ac[mi][ni] = __builtin_amdgcn_mfma_f32_16x16x32_bf16(afr[mi][kk], bfr[ni][kk], ac[mi][ni], 0, 0, 0);
}

static __device__ __forceinline__ void gemm8_core(
    unsigned short* lds,
    const unsigned short* __restrict__ A1, const unsigned short* __restrict__ A2,
    const unsigned short* __restrict__ B1, const unsigned short* __restrict__ B2,
    int K1, int K2,
    const unsigned short* __restrict__ bias, const unsigned short* __restrict__ resid,
    void* __restrict__ Cout, int outmode, int N, int m0, int n0,
    int a1shift, const unsigned short* __restrict__ zrow) {
  int tid = threadIdx.x;
  int lane = tid & 63, w = tid >> 6;
  int wm = w >> 2, wn = w & 3;
  int lr = lane & 15, g = lane >> 4;
  int col0 = g * 16;                 // byte col block of this lane's fragment
  int axor = (lr & 7) << 4;          // read-side swizzle (row&7 == lr&7 for all frag rows)
  int nk1 = K1 >> 6;                 // tiles in segment 1 (>= 2 for all call sites)
  int nk = (K1 + K2) >> 6;
  f32x4 acc[2][4][2] = {};
  bf16x8 afr[4][2], bfr0[2][2], bfr1[2][2];

  unsigned short* buf0 = lds;            // each buf: A @0, B0 @8192, B1 @16384 (ushorts)
  unsigned short* buf1 = lds + 24576;
  unsigned short* buf2 = lds + 49152;

  SPtrs sp;
  build_ptrs(sp, A1, B1, K1, a1shift, m0, n0, zrow, tid);

  // ---- prologue: stage tiles 0 and 1; loop's t=0 sync verifies tile 0 ----
  stage6(buf0, sp, tid);
  stage6(buf1, sp, tid);

  unsigned short* cur = buf0;
  unsigned short* nx1 = buf1;
  unsigned short* nx2 = buf2;
  for (int t = 0; t < nk; ++t) {
    // ---- single sync point per K-tile ----
    if (t < nk - 1) asm volatile("s_waitcnt vmcnt(6)" ::: "memory");
    else            asm volatile("s_waitcnt vmcnt(0)" ::: "memory");
    __builtin_amdgcn_s_barrier();
    asm volatile("" ::: "memory");     // no LDS reads hoist above the barrier

    // ---- reads first (critical path), then stage t+2, then MFMA ----
    rd_af(cur,         afr,  wm, lr, col0, axor);
    rd_bf(cur + 8192,  bfr0, wn, lr, col0, axor);
    rd_bf(cur + 16384, bfr1, wn, lr, col0, axor);
    if (t + 2 < nk) {
      if (t + 2 == nk1) build_ptrs(sp, A2, B2, K2, 0, m0, n0, zrow, tid);
      stage6(nx2, sp, tid);
    }
    __builtin_amdgcn_s_setprio(1);
    mfma16(afr, bfr0, acc[0]);
    mfma16(afr, bfr1, acc[1]);
    __builtin_amdgcn_s_setprio(0);

    unsigned short* tmp = cur; cur = nx1; nx1 = nx2; nx2 = tmp;
  }

  // ---- epilogue ----
  #pragma unroll
  for (int qn = 0; qn < 2; ++qn)
    #pragma unroll
    for (int mi = 0; mi < 4; ++mi) {
      int row0 = m0 + wm*64 + mi*16 + g*4;
      #pragma unroll
      for (int ni = 0; ni < 2; ++ni) {
        int col = n0 + qn*128 + wn*32 + ni*16 + lr;
        float bv = bias ? b2f(bias[col]) : 0.f;
        f32x4 a = acc[qn][mi][ni];
        if (outmode == 3) {
          int bb = row0 >> 11;
          int s0 = row0 & (S - 1);
          size_t base = ((size_t)bb * HID + col) * S + s0;
          ushort4v pk;
          #pragma unroll
          for (int j = 0; j < 4; ++j) pk[j] = f2b(a[j]);
          *(ushort4v*)((unsigned short*)Cout + base) = pk;
        } else {
          #pragma unroll
          for (int j = 0; j < 4; ++j) {
            size_t idx = (size_t)(row0 + j) * N + col;
            float v = a[j] + bv;
            if (resid) v += b2f(resid[idx]);
            if (outmode == 1) ((float*)Cout)[idx] = v;
            else ((unsigned short*)Cout)[idx] = f2b(v);
          }
        }
      }
    }
}

template<int SHIFT>
__launch_bounds__(512, 1)
__global__ void gemm8_bt(const unsigned short* __restrict__ A1,
                         const unsigned short* __restrict__ A2,
                         const unsigned short* __restrict__ B1,
                         const unsigned short* __restrict__ B2,
                         int K1, int K2,
                         const unsigned short* __restrict__ bias,
                         const unsigned short* __restrict__ resid,
                         void* __restrict__ Cout, int outmode, int N,
                         const unsigned short* __restrict__ zrow) {
  __shared__ __align__(16) unsigned short lds[73728];   // 144 KiB, 3 bufs
  gemm8_core(lds, A1, A2, B1, B2, K1, K2, bias, resid, Cout, outmode, N,
             blockIdx.x*128, blockIdx.y*256, SHIFT, zrow);
}

// two independent GEMM jobs in one dispatch; heavy job MUST be j0 (dispatched first)
struct GemmJob {
  const unsigned short *A1, *A2, *B1, *B2;
  int K1, K2;
  const unsigned short *bias;
  void* Cout; int outmode; int N; int nby; int a1shift;
};

__launch_bounds__(512, 1)
__global__ void gemm8_dual(GemmJob j0, GemmJob j1, const unsigned short* __restrict__ zrow) {
  __shared__ __align__(16) unsigned short lds[73728];
  int by = blockIdx.y;
  GemmJob j;
  if (by < j0.nby) { j = j0; } else { j = j1; by -= j0.nby; }
  gemm8_core(lds, j.A1, j.A2, j.B1, j.B2, j.K1, j.K2, j.bias, nullptr,
             j.Cout, j.outmode, j.N, blockIdx.x*128, by*256, j.a1shift, zrow);
}

// ---------------- RMSNorm over bf16 rows -> bf16 (single-pass, short8) ----------------
__global__ void rmsnorm_rows(const unsigned short* __restrict__ y,
                             const unsigned short* __restrict__ w,
                             unsigned short* __restrict__ out) {
  int r = blockIdx.x;
  int c8 = threadIdx.x * 8;               // 256 threads x 8 = 2048
  const unsigned short* yr = y + (size_t)r * HID;
  short8 v = *(const short8*)(yr + c8);
  float f[8];
  float ss = 0.f;
  #pragma unroll
  for (int e = 0; e < 8; ++e) { f[e] = b2f((unsigned short)v[e]); ss += f[e]*f[e]; }
  #pragma unroll
  for (int o = 32; o; o >>= 1) ss += __shfl_xor(ss, o);
  __shared__ float red[4];
  if ((threadIdx.x & 63) == 0) red[threadIdx.x >> 6] = ss;
  __syncthreads();
  float tot = red[0] + red[1] + red[2] + red[3];
  float scale = rsqrtf(tot / (float)HID + 1e-6f);
  short8 wv = *(const short8*)(w + c8);
  short8 o8;
  #pragma unroll
  for (int e = 0; e < 8; ++e) o8[e] = (short)f2b(f[e] * scale * b2f((unsigned short)wv[e]));
  *(short8*)(out + (size_t)r*HID + c8) = o8;
}

// ---------------- RoPE from fused qk output [r][4096]; head h = cols h*256..+255 ----------------
__global__ void rope_rearrange(const unsigned short* __restrict__ qkf,
                               const float* __restrict__ ctab, const float* __restrict__ stab,
                               unsigned short* __restrict__ qr, unsigned short* __restrict__ kr) {
  int r = blockIdx.x;
  int t = r & (S - 1);
  int h = threadIdx.x >> 4;
  int i4 = (threadIdx.x & 15) * 4;
  int pc = (i4 & 31) + ((i4 >> 5) << 6);    // permuted col of x1 for elems i4..i4+3 (same 32-block)
  const unsigned short* qk = qkf + (size_t)r * (2*HID) + h * 256;
  f32x4 c = *(const f32x4*)(ctab + t*64 + i4);
  f32x4 s = *(const f32x4*)(stab + t*64 + i4);
  ushort4v q1 = *(const ushort4v*)(qk + pc);
  ushort4v q2 = *(const ushort4v*)(qk + pc + 32);
  ushort4v k1 = *(const ushort4v*)(qk + 128 + pc);
  ushort4v k2 = *(const ushort4v*)(qk + 128 + pc + 32);
  size_t o = (size_t)r * HID + (size_t)h * HD;
  const float SC = 0.08838834764831845f * 1.44269504088896340f;  // 1/sqrt(128) * log2(e)
  ushort4v oq1, oq2, ok1, ok2;
  #pragma unroll
  for (int e = 0; e < 4; ++e) {
    float a = b2f(q1[e]), b = b2f(q2[e]);
    float x = b2f(k1[e]), y = b2f(k2[e]);
    oq1[e] = f2b((a*c[e] - b*s[e]) * SC);
    oq2[e] = f2b((b*c[e] + a*s[e]) * SC);
    ok1[e] = f2b(x*c[e] - y*s[e]);
    ok2[e] = f2b(y*c[e] + x*s[e]);
  }
  *(ushort4v*)(qr + o + i4)      = oq1;
  *(ushort4v*)(qr + o + 64 + i4) = oq2;
  *(ushort4v*)(kr + o + i4)      = ok1;
  *(ushort4v*)(kr + o + 64 + i4) = ok2;
}

// ---------------- MFMA causal flash attention ----------------
// 4 waves/block; wave owns 16 q rows; KV tile 64; swapped QK^T for lane-local softmax.
// K/V staged via global_load_lds (DMA) into double-buffered XOR-swizzled LDS: linear LDS
// dest + PRE-SWIZZLED per-lane global source (m173 pattern; swizzle is a within-row 16B
// permutation), swizzled ds_read. ONE sync point per tile: per-wave vmcnt(0) BEFORE the
// barrier => at barrier-release every wave's 8 DMA loads (issued a full tile earlier)
// have landed. WAR safe: next-tile stages go to the other buffer, whose last readers
// retired (lgkm-enforced by their MFMAs) before reaching this barrier.
// Removes kreg/vreg (32 VGPR -> no spill), 8 LDS-write instrs + 1 barrier per tile.
// LDS 72KB -> 2 blocks/CU; __launch_bounds__(256,2) -> 256-VGPR budget.
#define KT 64

__launch_bounds__(256, 2)
__global__ void attn_mfma(const unsigned short* __restrict__ Qr,
                          const unsigned short* __restrict__ Kr,
                          const unsigned short* __restrict__ Vt,
                          unsigned short* __restrict__ Out) {
  // [0,8192) K0 | [8192,16384) V0 | [16384,24576) K1 | [24576,32768) V1 | [32768,36864) P
  __shared__ __align__(16) unsigned short lds[36864];
  int tid = threadIdx.x, lane = tid & 63, w = tid >> 6;
  int bh = blockIdx.x;
  int b = bh >> 4, h = bh & 15;
  int qt = (int)gridDim.y - 1 - (int)blockIdx.y;   // big tiles dispatch first
  int q0 = qt * 64;
  size_t bS = (size_t)b * S;
  size_t ho = (size_t)h * HD;
  int lr = lane & 15, g = lane >> 4;
  int rsw = (lr & 7) << 3;                         // read-side swizzle (ushort units)
  bf16x8 bq[4];
  {
    int qrow = q0 + w*16 + lr;
    const unsigned short* qp = Qr + (bS + qrow)*HID + ho + g*8;
    #pragma unroll
    for (int kk = 0; kk < 4; ++kk) bq[kk] = *(const bf16x8*)(qp + kk*32);
  }
  // staging pointers (pre-swizzled source cols; advance per tile)
  const unsigned short* kp[4];
  const unsigned short* vp[4];
  #pragma unroll
  for (int j = 0; j < 4; ++j) {
    int c = w*4 + j;                       // chunk 0..15 (1KB each)
    int rk = c*4 + (lane >> 4);            // K row 0..63
    int sck = ((lane & 15) * 8) ^ ((rk & 7) << 3);
    kp[j] = Kr + (bS + rk)*HID + ho + sck;
    int rv = c*8 + (lane >> 3);            // V row (d) 0..127
    int scv = ((lane & 7) * 8) ^ ((rv & 7) << 3);
    vp[j] = Vt + ((size_t)b*HID + ho + rv)*S + scv;
  }
  int cdst = (w*4) * 512;                  // this wave's chunk-group dest (ushorts)
  unsigned short* curK = lds;
  unsigned short* curV = lds + 8192;
  unsigned short* nxtK = lds + 16384;
  unsigned short* nxtV = lds + 24576;
  // prologue: stage tile 0 -> cur
  #pragma unroll
  for (int j = 0; j < 4; ++j) {
    gload_lds16(kp[j], curK + cdst + j*512);
    gload_lds16(vp[j], curV + cdst + j*512);
    kp[j] += (size_t)KT * HID;
    vp[j] += KT;
  }
  f32x4 o[8] = {};                 // O: col(d)=lr+16*ni, row(q_local)=4g+reg
  float m = -1e30f, l = 0.f;
  unsigned short* PlW = lds + 32768 + w*1024;
  int ntiles = qt + 1;
  for (int kt = 0; kt < ntiles; ++kt) {
    // ---- single sync point: own DMA landed, then block-wide barrier ----
    asm volatile("s_waitcnt vmcnt(0)" ::: "memory");
    __builtin_amdgcn_s_barrier();
    asm volatile("" ::: "memory");
    if (kt + 1 < ntiles) {                 // issue next-tile DMA into the other buffer
      #pragma unroll
      for (int j = 0; j < 4; ++j) {
        gload_lds16(kp[j], nxtK + cdst + j*512);
        gload_lds16(vp[j], nxtV + cdst + j*512);
        kp[j] += (size_t)KT * HID;
        vp[j] += KT;
      }
    }
    f32x4 st[4] = {};
    __builtin_amdgcn_s_setprio(1);
    #pragma unroll
    for (int kk = 0; kk < 4; ++kk) {
      #pragma unroll
      for (int mi = 0; mi < 4; ++mi) {
        bf16x8 a = *(const bf16x8*)(&curK[(mi*16 + lr)*128 + ((kk*32 + g*8) ^ rsw)]);
        st[mi] = __builtin_amdgcn_mfma_f32_16x16x32_bf16(a, bq[kk], st[mi], 0, 0, 0);
      }
    }
    __builtin_amdgcn_s_setprio(0);
    bool lastt = (kt == ntiles - 1);
    float tm = -1e30f;
    #pragma unroll
    for (int mi = 0; mi < 4; ++mi)
      #pragma unroll
      for (int r = 0; r < 4; ++r) {
        float v = st[mi][r];
        if (lastt && (mi*16 + 4*g + r) > (w*16 + lr)) v = -1e30f;
        st[mi][r] = v;
        tm = fmaxf(tm, v);
      }
    tm = fmaxf(tm, __shfl_xor(tm, 16));
    tm = fmaxf(tm, __shfl_xor(tm, 32));
    if (!__all(tm - m <= 11.5f)) {
      float mn = fmaxf(m, tm);
      float sc = exp2f(m - mn);
      float s0 = __shfl(sc, 4*g+0), s1 = __shfl(sc, 4*g+1);
      float s2 = __shfl(sc, 4*g+2), s3 = __shfl(sc, 4*g+3);
      #pragma unroll
      for (int ni = 0; ni < 8; ++ni) {
        o[ni][0] *= s0; o[ni][1] *= s1; o[ni][2] *= s2; o[ni][3] *= s3;
      }
      l *= sc;
      m = mn;
    }
    float ts = 0.f;
    __bf16 pbf[4][4];
    #pragma unroll
    for (int mi = 0; mi < 4; ++mi)
      #pragma unroll
      for (int r = 0; r < 4; ++r) {
        float p = exp2f(st[mi][r] - m);
        ts += p;
        pbf[mi][r] = (__bf16)p;
      }
    ts += __shfl_xor(ts, 16);
    ts += __shfl_xor(ts, 32);
    l += ts;
    #pragma unroll
    for (int mi = 0; mi < 4; ++mi) {
      bf16x4 pk = { pbf[mi][0], pbf[mi][1], pbf[mi][2], pbf[mi][3] };
      *(bf16x4*)(&PlW[lr*64 + ((mi*16 + 4*g) ^ rsw)]) = pk;
    }
    asm volatile("" ::: "memory");   // compile-time fence: P stores before P reads
    __builtin_amdgcn_s_setprio(1);
    #pragma unroll
    for (int kk = 0; kk < 2; ++kk) {
      int pc = (kk*32 + g*8) ^ rsw;
      bf16x8 a = *(const bf16x8*)(&PlW[lr*64 + pc]);
      #pragma unroll
      for (int ni = 0; ni < 8; ++ni) {
        bf16x8 bv = *(const bf16x8*)(&curV[(ni*16 + lr)*64 + pc]);
        o[ni] = __builtin_amdgcn_mfma_f32_16x16x32_bf16(a, bv, o[ni], 0, 0, 0);
      }
    }
    __builtin_amdgcn_s_setprio(0);
    unsigned short* t0 = curK; curK = nxtK; nxtK = t0;
    unsigned short* t1 = curV; curV = nxtV; nxtV = t1;
  }
  float l0 = __shfl(l, 4*g+0), l1 = __shfl(l, 4*g+1);
  float l2 = __shfl(l, 4*g+2), l3 = __shfl(l, 4*g+3);
  float i0 = 1.f/l0, i1 = 1.f/l1, i2 = 1.f/l2, i3 = 1.f/l3;
  int rbase = q0 + w*16 + 4*g;
  #pragma unroll
  for (int ni = 0; ni < 8; ++ni) {
    size_t cbase = ho + ni*16 + lr;
    Out[(bS + rbase + 0)*HID + cbase] = f2b(o[ni][0]*i0);
    Out[(bS + rbase + 1)*HID + cbase] = f2b(o[ni][1]*i1);
    Out[(bS + rbase + 2)*HID + cbase] = f2b(o[ni][2]*i2);
    Out[(bS + rbase + 3)*HID + cbase] = f2b(o[ni][3]*i3);
  }
}

extern "C" void kernel_launch(void* const* d_in, const int* in_sizes, int n_in,
                              void* d_out, int out_size, void* d_ws, size_t ws_size,
                              hipStream_t stream) {
  const float* x_raw   = (const float*)d_in[0];
  const int* positions = (const int*)d_in[1];
  const float* wq_raw  = (const float*)d_in[2];
  const float* wk_raw  = (const float*)d_in[3];
  const float* wv_raw  = (const float*)d_in[4];
  const float* wo_raw  = (const float*)d_in[5];
  const float* c1w_raw = (const float*)d_in[6];
  const float* c1b_raw = (const float*)d_in[7];
  const float* c2w_raw = (const float*)d_in[8];
  const float* c2b_raw = (const float*)d_in[9];
  const float* rms_raw = (const float*)d_in[10];

  const size_t WS_NEEDED = 140000000;
  if (ws_size < WS_NEEDED) {
    long n = (long)out_size;
    fill_debug<<<dim3((unsigned)((n + 255) / 256)), dim3(256), 0, stream>>>((unsigned short*)d_out, n);
    return;
  }

  char* ws = (char*)d_ws;
  size_t off = 0;
  auto alloc = [&](size_t bytes) { char* p = ws + off; off += (bytes + 255) & ~(size_t)255; return p; };
  float* ctab          = (float*)alloc((size_t)S*64*4);
  float* stab          = (float*)alloc((size_t)S*64*4);
  unsigned short* wqkt = (unsigned short*)alloc((size_t)2*HID*HID*2);  // [wq^T ; wk^T], rope-permuted
  unsigned short* wvt  = (unsigned short*)alloc((size_t)HID*HID*2);
  unsigned short* wot  = (unsigned short*)alloc((size_t)HID*HID*2);
  unsigned short* w1t0 = (unsigned short*)alloc((size_t)1024*HID*2);
  unsigned short* w1t1 = (unsigned short*)alloc((size_t)1024*HID*2);
  unsigned short* w2t0 = (unsigned short*)alloc((size_t)HID*1024*2);
  unsigned short* w2t1 = (unsigned short*)alloc((size_t)HID*1024*2);
  unsigned short* xb   = (unsigned short*)alloc((size_t)ROWS*HID*2);   // reused as kr after conv2
  unsigned short* qrb  = (unsigned short*)alloc((size_t)ROWS*HID*2);   // q rotated
  unsigned short* o1   = (unsigned short*)alloc((size_t)ROWS*1024*2);
  unsigned short* yb   = (unsigned short*)alloc((size_t)ROWS*HID*2);   // reused as attn out
  unsigned short* hg   = (unsigned short*)alloc((size_t)ROWS*HID*2);
  unsigned short* qkf  = (unsigned short*)alloc((size_t)ROWS*2*HID*2); // fused q|k output
  unsigned short* vtg  = (unsigned short*)alloc((size_t)BATCH*HID*S*2);
  unsigned short* c1bb = (unsigned short*)alloc(1024*2);
  unsigned short* c2bb = (unsigned short*)alloc(2048*2);
  unsigned short* rmswb= (unsigned short*)alloc(2048*2);
  unsigned short* zpg  = (unsigned short*)alloc(8192*2);               // zero page (kk-advancing)
  unsigned short* krr  = xb;     // xb dead after conv2 (resid read)
  unsigned short* attn = yb;     // yb dead after rmsnorm

  dim3 b256(256);
  dim3 b512(512);
  prep_all<<<dim3(4096, 4), b256, 0, stream>>>(c1w_raw, c2w_raw, x_raw, positions,
                                               c1b_raw, c2b_raw, rms_raw,
                                               w1t0, w1t1, w2t0, w2t1, xb,
                                               ctab, stab, c1bb, c2bb, rmswb, zpg);
  transpose4<<<dim3(32,32,4), b256, 0, stream>>>(wq_raw, wk_raw, wv_raw, wo_raw,
                                                 wqkt, wqkt + (size_t)HID*HID, wvt, wot);
  // merged dispatch: conv1 (o1 = shift(xb)@W1_0^T + xb@W1_1^T + b1, N=1024, K=4096)  [HEAVY -> j0]
  //                + V-projection (vtg = xb@wv^T, Vt layout, N=2048, K=2048)
  {
    GemmJob j0 = { xb, xb, w1t0, w1t1, HID, HID, c1bb, o1, 0, 1024, 4, 1 };
    GemmJob j1 = { xb, xb, wvt,  wvt,  HID, 0,   nullptr, vtg, 3, HID, 8, 0 };
    gemm8_dual<<<dim3(ROWS/128, 12), b512, 0, stream>>>(j0, j1, zpg);
  }
  // conv2 + resid: yb = shift(o1)@W2_0^T + o1@W2_1^T + b2 + xb    [4096 x 2048]
  gemm8_bt<1><<<dim3(ROWS/128, HID/256), b512, 0, stream>>>(o1, o1, w2t0, w2t1, 1024, 1024, c2bb, xb, yb, 0, HID, zpg);
  rmsnorm_rows<<<dim3(ROWS), b256, 0, stream>>>(yb, rmswb, hg);
  // fused q|k projection: qkf = hg @ [wq|wk] (permuted weight cols)   [4096 x 4096]
  gemm8_bt<0><<<dim3(ROWS/128, (2*HID)/256), b512, 0, stream>>>(hg, hg, wqkt, wqkt, HID, 0, nullptr, nullptr, qkf, 0, 2*HID, nullptr);
  rope_rearrange<<<dim3(ROWS), b256, 0, stream>>>(qkf, ctab, stab, qrb, krr);
  attn_mfma<<<dim3(BATCH*HEADS, S/64), b256, 0, stream>>>(qrb, krr, vtg, attn);
  gemm8_bt<0><<<dim3(ROWS/128, HID/256), b512, 0, stream>>>(attn, attn, wot, wot, HID, 0, nullptr, nullptr, d_out, 1, HID, nullptr);
}